// Round 4
// baseline (638.946 us; speedup 1.0000x reference)
//
#include <hip/hip_runtime.h>
#include <cstdint>
#include <cstddef>

#define D_   384
#define Hn   6
#define HDm  64
#define T_   256
#define B_   128
#define NROW (B_ * T_)   // 32768

typedef __bf16  bf16x8 __attribute__((ext_vector_type(8)));
typedef float   f32x4  __attribute__((ext_vector_type(4)));
typedef const __attribute__((address_space(1))) void gvoid;
typedef __attribute__((address_space(3))) void lvoid;

// ---------- helpers ----------
__device__ inline uint32_t bf16rn(float f) {
  uint32_t u = __float_as_uint(f);
  return (u + 0x7FFFu + ((u >> 16) & 1u)) >> 16;
}

// ---------- LayerNorm: fp32 in -> bf16 out, one 128-thread block per row ----------
__global__ __launch_bounds__(128) void ln_kernel(const float* __restrict__ x,
                                                 const float* __restrict__ g,
                                                 const float* __restrict__ b,
                                                 uint16_t* __restrict__ out) {
  int row = blockIdx.x, tid = threadIdx.x;
  const float* xr = x + (size_t)row * D_;
  float v0 = xr[tid], v1 = xr[tid + 128], v2 = xr[tid + 256];
  float s  = v0 + v1 + v2;
  float ss = v0 * v0 + v1 * v1 + v2 * v2;
#pragma unroll
  for (int off = 32; off > 0; off >>= 1) {
    s  += __shfl_down(s, off);
    ss += __shfl_down(ss, off);
  }
  __shared__ float red[4];
  if ((tid & 63) == 0) { red[(tid >> 6) * 2] = s; red[(tid >> 6) * 2 + 1] = ss; }
  __syncthreads();
  float S = red[0] + red[2], SS = red[1] + red[3];
  float mu  = S * (1.0f / D_);
  float var = SS * (1.0f / D_) - mu * mu;
  float inv = rsqrtf(var + 1e-5f);
  uint16_t* orow = out + (size_t)row * D_;
  orow[tid]       = (uint16_t)bf16rn((v0 - mu) * inv * g[tid]       + b[tid]);
  orow[tid + 128] = (uint16_t)bf16rn((v1 - mu) * inv * g[tid + 128] + b[tid + 128]);
  orow[tid + 256] = (uint16_t)bf16rn((v2 - mu) * inv * g[tid + 256] + b[tid + 256]);
}

// ---------- pack Wq/Wk/Wv [H,D,HD] -> bf16 Wt[col=1152][d=384] (K-contiguous) ----------
__global__ __launch_bounds__(256) void pack_qkv_w(const float* __restrict__ Wq,
                                                  const float* __restrict__ Wk,
                                                  const float* __restrict__ Wv,
                                                  uint16_t* __restrict__ Wo) {
  int idx = blockIdx.x * 256 + threadIdx.x;      // 1152*384 total
  if (idx >= 1152 * D_) return;
  int col = idx / D_, d = idx % D_;
  int which = col / 384, c2 = col % 384;
  int h = c2 / HDm, k = c2 % HDm;
  const float* W = (which == 0) ? Wq : (which == 1) ? Wk : Wv;
  Wo[idx] = (uint16_t)bf16rn(W[((size_t)h * D_ + d) * HDm + k]);
}

// ---------- transpose-pack W[K,N] -> bf16 Wt[N,K] ----------
__global__ __launch_bounds__(256) void pack_wt(const float* __restrict__ W,
                                               uint16_t* __restrict__ Wt,
                                               int K, int N) {
  int idx = blockIdx.x * 256 + threadIdx.x;
  if (idx >= K * N) return;
  int n = idx / K, k = idx % K;
  Wt[idx] = (uint16_t)bf16rn(W[(size_t)k * N + n]);
}

// ---------- bf16 MFMA GEMM: C[M,N] = A[M,K] @ Bt[N,K]^T (+bias)(relu)(+resid) ----------
// 128x128 tile, BK=64, 4 waves, each wave 64x64 via 4x4 mfma_f32_16x16x32_bf16.
// LDS chunk-XOR swizzle: LDS slot (row, cc) holds global chunk (row, cc ^ (row&7)).
// Grid: x = M-tiles (so same-A blocks share an XCD), y = N-tiles.
__global__ __launch_bounds__(256) void gemm_bf16(const uint16_t* __restrict__ A,
                                                 const uint16_t* __restrict__ Bt,
                                                 const float* __restrict__ bias,
                                                 const float* __restrict__ resid,
                                                 void* __restrict__ Cout,
                                                 int M, int N, int K,
                                                 int relu, int store_f32) {
  __shared__ uint16_t As[128 * 64];   // 16 KB
  __shared__ uint16_t Bs[128 * 64];   // 16 KB
  int tid = threadIdx.x;
  int bm = blockIdx.x * 128, bn = blockIdx.y * 128;
  int lane = tid & 63, wave = tid >> 6;
  int wm = (wave >> 1) << 6;
  int wn = (wave & 1) << 6;
  int lr = lane & 15;                 // row-within-16
  int q  = lane >> 4;                 // k-chunk selector
  int r0 = q << 2;                    // C row base within 16
  int sw = lr & 7;                    // read-side swizzle (row&7 == lr&7)

  f32x4 acc[4][4];
  const f32x4 zero = {0.f, 0.f, 0.f, 0.f};
#pragma unroll
  for (int i = 0; i < 4; ++i)
#pragma unroll
    for (int j = 0; j < 4; ++j) acc[i][j] = zero;

  int c0a = (q ^ sw) << 3;            // ks=0 chunk byte-elem offset
  int c1a = ((4 | q) ^ sw) << 3;      // ks=1

  for (int k0 = 0; k0 < K; k0 += 64) {
    __syncthreads();
#pragma unroll
    for (int t = 0; t < 4; ++t) {
      int c = t * 256 + tid;          // 1024 chunks of 16 B per buffer
      int row = c >> 3, cc = c & 7;
      int gc = cc ^ (row & 7);
      const uint16_t* ga = A  + (size_t)(bm + row) * K + (k0 + gc * 8);
      const uint16_t* gb = Bt + (size_t)(bn + row) * K + (k0 + gc * 8);
      __builtin_amdgcn_global_load_lds((gvoid*)ga, (lvoid*)((char*)As + c * 16), 16, 0, 0);
      __builtin_amdgcn_global_load_lds((gvoid*)gb, (lvoid*)((char*)Bs + c * 16), 16, 0, 0);
    }
    __syncthreads();

    bf16x8 af[2][4], bfr[2][4];
#pragma unroll
    for (int i = 0; i < 4; ++i) {
      int ra = (wm + i * 16 + lr) * 64;
      af[0][i] = *(const bf16x8*)&As[ra + c0a];
      af[1][i] = *(const bf16x8*)&As[ra + c1a];
      int rb = (wn + i * 16 + lr) * 64;
      bfr[0][i] = *(const bf16x8*)&Bs[rb + c0a];
      bfr[1][i] = *(const bf16x8*)&Bs[rb + c1a];
    }
#pragma unroll
    for (int ks = 0; ks < 2; ++ks)
#pragma unroll
      for (int i = 0; i < 4; ++i)
#pragma unroll
        for (int j = 0; j < 4; ++j)
          acc[i][j] = __builtin_amdgcn_mfma_f32_16x16x32_bf16(af[ks][i], bfr[ks][j], acc[i][j], 0, 0, 0);
  }

#pragma unroll
  for (int i = 0; i < 4; ++i) {
#pragma unroll
    for (int r = 0; r < 4; ++r) {
      int rr = bm + wm + i * 16 + r0 + r;
#pragma unroll
      for (int j = 0; j < 4; ++j) {
        int col = bn + wn + j * 16 + lr;
        float v = acc[i][j][r];
        if (bias)  v += bias[col];
        if (relu)  v = fmaxf(v, 0.0f);
        if (resid) v += resid[(size_t)rr * N + col];
        if (store_f32) ((float*)Cout)[(size_t)rr * N + col] = v;
        else           ((uint16_t*)Cout)[(size_t)rr * N + col] = (uint16_t)bf16rn(v);
      }
    }
  }
}

// ---------- MFMA flash attention: one block per (b,h), 4 waves, wave w = rows w*64..w*64+63 ----------
// qkv (bf16) row (b*T+t): cols [0,384)=q(h*64+d), [384,768)=k, [768,1152)=v
__global__ __launch_bounds__(256, 2) void attn_mfma(const uint16_t* __restrict__ qkv,
                                                    uint16_t* __restrict__ o) {
  __shared__ uint16_t Kt[64 * 72];        // K-tile [s][d], pad 72 (9216 B)
  __shared__ uint16_t Vt[64 * 72];        // V-tile transposed [d][s], pad 72 (9216 B)
  __shared__ uint16_t Pb[4 * 64 * 72];    // per-wave P staging (36864 B)
  int bh = blockIdx.x;
  int b = bh / Hn, h = bh % Hn;
  int tid = threadIdx.x;
  int lane = tid & 63, w = tid >> 6;
  int ln = lane & 15, q = lane >> 4;
  int kq = q * 8;
  int m0 = w * 64;
  const uint16_t* base = qkv + (size_t)b * T_ * 1152;

  bf16x8 af[4][2];
#pragma unroll
  for (int i = 0; i < 4; ++i)
#pragma unroll
    for (int ks = 0; ks < 2; ++ks)
      af[i][ks] = *(const bf16x8*)(base + (size_t)(m0 + i * 16 + ln) * 1152 + h * HDm + ks * 32 + kq);

  f32x4 o_[4][4], m_[4], l_[4];
  const f32x4 zero = {0.f, 0.f, 0.f, 0.f};
#pragma unroll
  for (int i = 0; i < 4; ++i) {
    m_[i] = {-1e30f, -1e30f, -1e30f, -1e30f};
    l_[i] = zero;
#pragma unroll
    for (int n = 0; n < 4; ++n) o_[i][n] = zero;
  }
  const float cs = 0.07362222f;  // (1/sqrt(384)) * log2(e)

  for (int jt = 0; jt < 4; ++jt) {
    if (jt) __syncthreads();
#pragma unroll
    for (int t = 0; t < 2; ++t) {
      int c = t * 256 + tid;
      int s = c >> 3, d0 = (c & 7) << 3;
      *(uint4*)&Kt[s * 72 + d0] =
          *(const uint4*)(base + (size_t)(jt * 64 + s) * 1152 + 384 + h * HDm + d0);
    }
    {
      int sv = tid & 63, dv = (tid >> 6) << 4;
      const uint16_t* gv = base + (size_t)(jt * 64 + sv) * 1152 + 768 + h * HDm + dv;
      uint16_t tmp[16];
      *(uint4*)&tmp[0] = *(const uint4*)gv;
      *(uint4*)&tmp[8] = *(const uint4*)(gv + 8);
#pragma unroll
      for (int jj = 0; jj < 16; ++jj) Vt[(dv + jj) * 72 + sv] = tmp[jj];
    }
    __syncthreads();

    if (w >= jt) {
      f32x4 s2[4][4];
#pragma unroll
      for (int i = 0; i < 4; ++i)
#pragma unroll
        for (int j = 0; j < 4; ++j) s2[i][j] = zero;
#pragma unroll
      for (int ks = 0; ks < 2; ++ks) {
        bf16x8 bf[4];
#pragma unroll
        for (int j = 0; j < 4; ++j)
          bf[j] = *(const bf16x8*)&Kt[(j * 16 + ln) * 72 + ks * 32 + kq];
#pragma unroll
        for (int i = 0; i < 4; ++i)
#pragma unroll
          for (int j = 0; j < 4; ++j)
            s2[i][j] = __builtin_amdgcn_mfma_f32_16x16x32_bf16(af[i][ks], bf[j], s2[i][j], 0, 0, 0);
      }
#pragma unroll
      for (int i = 0; i < 4; ++i) {
#pragma unroll
        for (int j = 0; j < 4; ++j)
#pragma unroll
          for (int r = 0; r < 4; ++r) s2[i][j][r] *= cs;
        if (jt == w) {
#pragma unroll
          for (int j = 0; j < 4; ++j)
#pragma unroll
            for (int r = 0; r < 4; ++r)
              if (j * 16 + ln > i * 16 + q * 4 + r) s2[i][j][r] = -1e30f;
        }
        f32x4 rm;
#pragma unroll
        for (int r = 0; r < 4; ++r)
          rm[r] = fmaxf(fmaxf(s2[i][0][r], s2[i][1][r]), fmaxf(s2[i][2][r], s2[i][3][r]));
#pragma unroll
        for (int off = 1; off < 16; off <<= 1)
#pragma unroll
          for (int r = 0; r < 4; ++r)
            rm[r] = fmaxf(rm[r], __shfl_xor(rm[r], off));
        f32x4 mn, al, ps;
#pragma unroll
        for (int r = 0; r < 4; ++r) {
          mn[r] = fmaxf(m_[i][r], rm[r]);
          al[r] = exp2f(m_[i][r] - mn[r]);
          ps[r] = 0.f;
        }
        m_[i] = mn;
#pragma unroll
        for (int j = 0; j < 4; ++j)
#pragma unroll
          for (int r = 0; r < 4; ++r) {
            float p = exp2f(s2[i][j][r] - mn[r]);
            s2[i][j][r] = p;
            ps[r] += p;
          }
#pragma unroll
        for (int r = 0; r < 4; ++r) l_[i][r] = l_[i][r] * al[r] + ps[r];
#pragma unroll
        for (int n = 0; n < 4; ++n)
#pragma unroll
          for (int r = 0; r < 4; ++r) o_[i][n][r] *= al[r];
#pragma unroll
        for (int j = 0; j < 4; ++j)
#pragma unroll
          for (int r = 0; r < 4; ++r)
            Pb[w * 4608 + (i * 16 + q * 4 + r) * 72 + j * 16 + ln] =
                (uint16_t)bf16rn(s2[i][j][r]);
      }
      bf16x8 pa[4][2];
#pragma unroll
      for (int i = 0; i < 4; ++i)
#pragma unroll
        for (int ks = 0; ks < 2; ++ks)
          pa[i][ks] = *(const bf16x8*)&Pb[w * 4608 + (i * 16 + ln) * 72 + ks * 32 + kq];
#pragma unroll
      for (int n = 0; n < 4; ++n) {
        bf16x8 bv0 = *(const bf16x8*)&Vt[(n * 16 + ln) * 72 + kq];
        bf16x8 bv1 = *(const bf16x8*)&Vt[(n * 16 + ln) * 72 + 32 + kq];
#pragma unroll
        for (int i = 0; i < 4; ++i) {
          o_[i][n] = __builtin_amdgcn_mfma_f32_16x16x32_bf16(pa[i][0], bv0, o_[i][n], 0, 0, 0);
          o_[i][n] = __builtin_amdgcn_mfma_f32_16x16x32_bf16(pa[i][1], bv1, o_[i][n], 0, 0, 0);
        }
      }
    }
  }
#pragma unroll
  for (int i = 0; i < 4; ++i) {
    f32x4 lt = l_[i];
#pragma unroll
    for (int off = 1; off < 16; off <<= 1)
#pragma unroll
      for (int r = 0; r < 4; ++r) lt[r] += __shfl_xor(lt[r], off);
#pragma unroll
    for (int r = 0; r < 4; ++r) {
      float inv = 1.0f / lt[r];
      int row = b * T_ + m0 + i * 16 + q * 4 + r;
      uint16_t* op = o + (size_t)row * D_ + h * HDm;
#pragma unroll
      for (int n = 0; n < 4; ++n)
        op[n * 16 + ln] = (uint16_t)bf16rn(o_[i][n][r] * inv);
    }
  }
}

extern "C" void kernel_launch(void* const* d_in, const int* in_sizes, int n_in,
                              void* d_out, int out_size, void* d_ws, size_t ws_size,
                              hipStream_t stream) {
  const float* x   = (const float*)d_in[0];
  const float* Wq  = (const float*)d_in[1];
  const float* Wk  = (const float*)d_in[2];
  const float* Wv  = (const float*)d_in[3];
  const float* Wp  = (const float*)d_in[4];
  const float* bp  = (const float*)d_in[5];
  const float* W1  = (const float*)d_in[6];
  const float* b1  = (const float*)d_in[7];
  const float* W2  = (const float*)d_in[8];
  const float* b2  = (const float*)d_in[9];
  const float* g1  = (const float*)d_in[10];
  const float* be1 = (const float*)d_in[11];
  const float* g2  = (const float*)d_in[12];
  const float* be2 = (const float*)d_in[13];
  float* out = (float*)d_out;

  char* ws = (char*)d_ws;
  uint16_t* hbuf  = (uint16_t*)ws;
  uint16_t* qkv   = (uint16_t*)(ws + 25165824ull);
  uint16_t* ob    = (uint16_t*)(ws + 100663296ull);
  uint16_t* ff1   = qkv;
  uint16_t* Wqkvt = (uint16_t*)(ws + 125829120ull);
  uint16_t* Wpt   = (uint16_t*)(ws + 126713856ull);
  uint16_t* W1t   = (uint16_t*)(ws + 127008768ull);
  uint16_t* W2t   = (uint16_t*)(ws + 128188416ull);

  // 1. pack weights to bf16, K-contiguous
  pack_qkv_w<<<(1152 * D_ + 255) / 256, 256, 0, stream>>>(Wq, Wk, Wv, Wqkvt);
  pack_wt<<<(384 * 384 + 255) / 256, 256, 0, stream>>>(Wp, Wpt, 384, 384);
  pack_wt<<<(384 * 1536 + 255) / 256, 256, 0, stream>>>(W1, W1t, 384, 1536);
  pack_wt<<<(1536 * 384 + 255) / 256, 256, 0, stream>>>(W2, W2t, 1536, 384);
  // 2. LN1: x -> h (bf16)
  ln_kernel<<<NROW, 128, 0, stream>>>(x, g1, be1, hbuf);
  // 3. QKV projection: [32768,384] @ [384,1152] -> bf16   (grid: x=M-tiles, y=N-tiles)
  gemm_bf16<<<dim3(NROW / 128, 1152 / 128), 256, 0, stream>>>(
      hbuf, Wqkvt, nullptr, nullptr, qkv, NROW, 1152, 384, 0, 0);
  // 4. MFMA flash attention -> ob (bf16)
  attn_mfma<<<B_ * Hn, 256, 0, stream>>>(qkv, ob);
  // 5. x1 = x + ob@Wp + bp  -> d_out (fp32)
  gemm_bf16<<<dim3(NROW / 128, 384 / 128), 256, 0, stream>>>(
      ob, Wpt, bp, x, out, NROW, 384, 384, 0, 1);
  // 6. LN2: x1 -> h (bf16)
  ln_kernel<<<NROW, 128, 0, stream>>>(out, g2, be2, hbuf);
  // 7. FF1 + ReLU: [32768,384] @ [384,1536] -> bf16
  gemm_bf16<<<dim3(NROW / 128, 1536 / 128), 256, 0, stream>>>(
      hbuf, W1t, b1, nullptr, ff1, NROW, 1536, 384, 1, 0);
  // 8. out = x1 + ff1@W2 + b2 -> d_out (fp32)
  gemm_bf16<<<dim3(NROW / 128, 384 / 128), 256, 0, stream>>>(
      ff1, W2t, b2, out, out, NROW, 384, 1536, 0, 1);
}

// Round 5
// 540.560 us; speedup vs baseline: 1.1820x; 1.1820x over previous
//
#include <hip/hip_runtime.h>
#include <cstdint>
#include <cstddef>

#define D_   384
#define Hn   6
#define HDm  64
#define T_   256
#define B_   128
#define NROW (B_ * T_)   // 32768

typedef __bf16  bf16x8 __attribute__((ext_vector_type(8)));
typedef float   f32x4  __attribute__((ext_vector_type(4)));
typedef const __attribute__((address_space(1))) void gvoid;
typedef __attribute__((address_space(3))) void lvoid;

// ---------- helpers ----------
__device__ inline uint32_t bf16rn(float f) {
  uint32_t u = __float_as_uint(f);
  return (u + 0x7FFFu + ((u >> 16) & 1u)) >> 16;
}

// ---------- LayerNorm: fp32 in -> bf16 out, one 128-thread block per row ----------
__global__ __launch_bounds__(128) void ln_kernel(const float* __restrict__ x,
                                                 const float* __restrict__ g,
                                                 const float* __restrict__ b,
                                                 uint16_t* __restrict__ out) {
  int row = blockIdx.x, tid = threadIdx.x;
  const float* xr = x + (size_t)row * D_;
  float v0 = xr[tid], v1 = xr[tid + 128], v2 = xr[tid + 256];
  float s  = v0 + v1 + v2;
  float ss = v0 * v0 + v1 * v1 + v2 * v2;
#pragma unroll
  for (int off = 32; off > 0; off >>= 1) {
    s  += __shfl_down(s, off);
    ss += __shfl_down(ss, off);
  }
  __shared__ float red[4];
  if ((tid & 63) == 0) { red[(tid >> 6) * 2] = s; red[(tid >> 6) * 2 + 1] = ss; }
  __syncthreads();
  float S = red[0] + red[2], SS = red[1] + red[3];
  float mu  = S * (1.0f / D_);
  float var = SS * (1.0f / D_) - mu * mu;
  float inv = rsqrtf(var + 1e-5f);
  uint16_t* orow = out + (size_t)row * D_;
  orow[tid]       = (uint16_t)bf16rn((v0 - mu) * inv * g[tid]       + b[tid]);
  orow[tid + 128] = (uint16_t)bf16rn((v1 - mu) * inv * g[tid + 128] + b[tid + 128]);
  orow[tid + 256] = (uint16_t)bf16rn((v2 - mu) * inv * g[tid + 256] + b[tid + 256]);
}

// ---------- pack Wq/Wk/Wv [H,D,HD] -> bf16 Wt[col=1152][d=384] (K-contiguous) ----------
__global__ __launch_bounds__(256) void pack_qkv_w(const float* __restrict__ Wq,
                                                  const float* __restrict__ Wk,
                                                  const float* __restrict__ Wv,
                                                  uint16_t* __restrict__ Wo) {
  int idx = blockIdx.x * 256 + threadIdx.x;      // 1152*384 total
  if (idx >= 1152 * D_) return;
  int col = idx / D_, d = idx % D_;
  int which = col / 384, c2 = col % 384;
  int h = c2 / HDm, k = c2 % HDm;
  const float* W = (which == 0) ? Wq : (which == 1) ? Wk : Wv;
  Wo[idx] = (uint16_t)bf16rn(W[((size_t)h * D_ + d) * HDm + k]);
}

// ---------- transpose-pack W[K,N] -> bf16 Wt[N,K] ----------
__global__ __launch_bounds__(256) void pack_wt(const float* __restrict__ W,
                                               uint16_t* __restrict__ Wt,
                                               int K, int N) {
  int idx = blockIdx.x * 256 + threadIdx.x;
  if (idx >= K * N) return;
  int n = idx / K, k = idx % K;
  Wt[idx] = (uint16_t)bf16rn(W[(size_t)k * N + n]);
}

// ---------- bf16 MFMA GEMM: C[M,N] = A[M,K] @ Bt[N,K]^T (+bias)(relu)(+resid) ----------
// 128x128 tile, BK=32, 4 waves, each wave 64x64 via 4x4 mfma_f32_16x16x32_bf16.
// LDS chunk-XOR swizzle: LDS slot (row, cc) holds global chunk (row, cc ^ (row&3));
// turns the 4-way staging-read bank conflict into free 2-way (m136).
// Grid: x = M-tiles (256%8==0 so same-A blocks share an XCD), y = N-tiles.
__global__ __launch_bounds__(256) void gemm_bf16(const uint16_t* __restrict__ A,
                                                 const uint16_t* __restrict__ Bt,
                                                 const float* __restrict__ bias,
                                                 const float* __restrict__ resid,
                                                 void* __restrict__ Cout,
                                                 int M, int N, int K,
                                                 int relu, int store_f32) {
  __shared__ uint16_t As[128 * 32];   // 8 KB
  __shared__ uint16_t Bs[128 * 32];   // 8 KB
  int tid = threadIdx.x;
  int bm = blockIdx.x * 128, bn = blockIdx.y * 128;
  int lane = tid & 63, wave = tid >> 6;
  int wm = (wave >> 1) << 6;
  int wn = (wave & 1) << 6;
  int lr = lane & 15;                 // row-within-16
  int q  = lane >> 4;                 // k-chunk selector (0..3)
  int r0 = q << 2;                    // C row base within 16
  int rd_off = (q ^ (lr & 3)) << 3;   // swizzled chunk elem offset within row

  f32x4 acc[4][4];
  const f32x4 zero = {0.f, 0.f, 0.f, 0.f};
#pragma unroll
  for (int i = 0; i < 4; ++i)
#pragma unroll
    for (int j = 0; j < 4; ++j) acc[i][j] = zero;

  for (int k0 = 0; k0 < K; k0 += 32) {
    __syncthreads();
#pragma unroll
    for (int t = 0; t < 2; ++t) {
      int c = t * 256 + tid;          // 512 chunks of 16 B per buffer
      int row = c >> 2, cc = c & 3;
      int gc = cc ^ (row & 3);
      const uint16_t* ga = A  + (size_t)(bm + row) * K + (k0 + gc * 8);
      const uint16_t* gb = Bt + (size_t)(bn + row) * K + (k0 + gc * 8);
      __builtin_amdgcn_global_load_lds((gvoid*)ga, (lvoid*)((char*)As + c * 16), 16, 0, 0);
      __builtin_amdgcn_global_load_lds((gvoid*)gb, (lvoid*)((char*)Bs + c * 16), 16, 0, 0);
    }
    __syncthreads();

    bf16x8 af[4], bfr[4];
#pragma unroll
    for (int i = 0; i < 4; ++i)
      af[i] = *(const bf16x8*)&As[(wm + i * 16 + lr) * 32 + rd_off];
#pragma unroll
    for (int j = 0; j < 4; ++j)
      bfr[j] = *(const bf16x8*)&Bs[(wn + j * 16 + lr) * 32 + rd_off];
#pragma unroll
    for (int i = 0; i < 4; ++i)
#pragma unroll
      for (int j = 0; j < 4; ++j)
        acc[i][j] = __builtin_amdgcn_mfma_f32_16x16x32_bf16(af[i], bfr[j], acc[i][j], 0, 0, 0);
  }

#pragma unroll
  for (int i = 0; i < 4; ++i) {
#pragma unroll
    for (int r = 0; r < 4; ++r) {
      int rr = bm + wm + i * 16 + r0 + r;
#pragma unroll
      for (int j = 0; j < 4; ++j) {
        int col = bn + wn + j * 16 + lr;
        float v = acc[i][j][r];
        if (bias)  v += bias[col];
        if (relu)  v = fmaxf(v, 0.0f);
        if (resid) v += resid[(size_t)rr * N + col];
        if (store_f32) ((float*)Cout)[(size_t)rr * N + col] = v;
        else           ((uint16_t*)Cout)[(size_t)rr * N + col] = (uint16_t)bf16rn(v);
      }
    }
  }
}

// ---------- MFMA flash attention: one block per (b,h), 4 waves, wave w = rows w*64..w*64+63 ----------
// qkv (bf16) row (b*T+t): cols [0,384)=q(h*64+d), [384,768)=k, [768,1152)=v
__global__ __launch_bounds__(256, 2) void attn_mfma(const uint16_t* __restrict__ qkv,
                                                    uint16_t* __restrict__ o) {
  __shared__ uint16_t Kt[64 * 72];        // K-tile [s][d], pad 72 (9216 B)
  __shared__ uint16_t Vt[64 * 72];        // V-tile transposed [d][s], pad 72 (9216 B)
  __shared__ uint16_t Pb[4 * 64 * 72];    // per-wave P staging (36864 B)
  int bh = blockIdx.x;
  int b = bh / Hn, h = bh % Hn;
  int tid = threadIdx.x;
  int lane = tid & 63, w = tid >> 6;
  int ln = lane & 15, q = lane >> 4;
  int kq = q * 8;
  int m0 = w * 64;
  const uint16_t* base = qkv + (size_t)b * T_ * 1152;

  bf16x8 af[4][2];
#pragma unroll
  for (int i = 0; i < 4; ++i)
#pragma unroll
    for (int ks = 0; ks < 2; ++ks)
      af[i][ks] = *(const bf16x8*)(base + (size_t)(m0 + i * 16 + ln) * 1152 + h * HDm + ks * 32 + kq);

  f32x4 o_[4][4], m_[4], l_[4];
  const f32x4 zero = {0.f, 0.f, 0.f, 0.f};
#pragma unroll
  for (int i = 0; i < 4; ++i) {
    m_[i] = {-1e30f, -1e30f, -1e30f, -1e30f};
    l_[i] = zero;
#pragma unroll
    for (int n = 0; n < 4; ++n) o_[i][n] = zero;
  }
  const float cs = 0.07362222f;  // (1/sqrt(384)) * log2(e)

  for (int jt = 0; jt < 4; ++jt) {
    if (jt) __syncthreads();
#pragma unroll
    for (int t = 0; t < 2; ++t) {
      int c = t * 256 + tid;
      int s = c >> 3, d0 = (c & 7) << 3;
      *(uint4*)&Kt[s * 72 + d0] =
          *(const uint4*)(base + (size_t)(jt * 64 + s) * 1152 + 384 + h * HDm + d0);
    }
    {
      int sv = tid & 63, dv = (tid >> 6) << 4;
      const uint16_t* gv = base + (size_t)(jt * 64 + sv) * 1152 + 768 + h * HDm + dv;
      uint16_t tmp[16];
      *(uint4*)&tmp[0] = *(const uint4*)gv;
      *(uint4*)&tmp[8] = *(const uint4*)(gv + 8);
#pragma unroll
      for (int jj = 0; jj < 16; ++jj) Vt[(dv + jj) * 72 + sv] = tmp[jj];
    }
    __syncthreads();

    if (w >= jt) {
      f32x4 s2[4][4];
#pragma unroll
      for (int i = 0; i < 4; ++i)
#pragma unroll
        for (int j = 0; j < 4; ++j) s2[i][j] = zero;
#pragma unroll
      for (int ks = 0; ks < 2; ++ks) {
        bf16x8 bf[4];
#pragma unroll
        for (int j = 0; j < 4; ++j)
          bf[j] = *(const bf16x8*)&Kt[(j * 16 + ln) * 72 + ks * 32 + kq];
#pragma unroll
        for (int i = 0; i < 4; ++i)
#pragma unroll
          for (int j = 0; j < 4; ++j)
            s2[i][j] = __builtin_amdgcn_mfma_f32_16x16x32_bf16(af[i][ks], bf[j], s2[i][j], 0, 0, 0);
      }
#pragma unroll
      for (int i = 0; i < 4; ++i) {
#pragma unroll
        for (int j = 0; j < 4; ++j)
#pragma unroll
          for (int r = 0; r < 4; ++r) s2[i][j][r] *= cs;
        if (jt == w) {
#pragma unroll
          for (int j = 0; j < 4; ++j)
#pragma unroll
            for (int r = 0; r < 4; ++r)
              if (j * 16 + ln > i * 16 + q * 4 + r) s2[i][j][r] = -1e30f;
        }
        f32x4 rm;
#pragma unroll
        for (int r = 0; r < 4; ++r)
          rm[r] = fmaxf(fmaxf(s2[i][0][r], s2[i][1][r]), fmaxf(s2[i][2][r], s2[i][3][r]));
#pragma unroll
        for (int off = 1; off < 16; off <<= 1)
#pragma unroll
          for (int r = 0; r < 4; ++r)
            rm[r] = fmaxf(rm[r], __shfl_xor(rm[r], off));
        f32x4 mn, al, ps;
#pragma unroll
        for (int r = 0; r < 4; ++r) {
          mn[r] = fmaxf(m_[i][r], rm[r]);
          al[r] = exp2f(m_[i][r] - mn[r]);
          ps[r] = 0.f;
        }
        m_[i] = mn;
#pragma unroll
        for (int j = 0; j < 4; ++j)
#pragma unroll
          for (int r = 0; r < 4; ++r) {
            float p = exp2f(s2[i][j][r] - mn[r]);
            s2[i][j][r] = p;
            ps[r] += p;
          }
#pragma unroll
        for (int r = 0; r < 4; ++r) l_[i][r] = l_[i][r] * al[r] + ps[r];
#pragma unroll
        for (int n = 0; n < 4; ++n)
#pragma unroll
          for (int r = 0; r < 4; ++r) o_[i][n][r] *= al[r];
#pragma unroll
        for (int j = 0; j < 4; ++j)
#pragma unroll
          for (int r = 0; r < 4; ++r)
            Pb[w * 4608 + (i * 16 + q * 4 + r) * 72 + j * 16 + ln] =
                (uint16_t)bf16rn(s2[i][j][r]);
      }
      bf16x8 pa[4][2];
#pragma unroll
      for (int i = 0; i < 4; ++i)
#pragma unroll
        for (int ks = 0; ks < 2; ++ks)
          pa[i][ks] = *(const bf16x8*)&Pb[w * 4608 + (i * 16 + ln) * 72 + ks * 32 + kq];
#pragma unroll
      for (int n = 0; n < 4; ++n) {
        bf16x8 bv0 = *(const bf16x8*)&Vt[(n * 16 + ln) * 72 + kq];
        bf16x8 bv1 = *(const bf16x8*)&Vt[(n * 16 + ln) * 72 + 32 + kq];
#pragma unroll
        for (int i = 0; i < 4; ++i) {
          o_[i][n] = __builtin_amdgcn_mfma_f32_16x16x32_bf16(pa[i][0], bv0, o_[i][n], 0, 0, 0);
          o_[i][n] = __builtin_amdgcn_mfma_f32_16x16x32_bf16(pa[i][1], bv1, o_[i][n], 0, 0, 0);
        }
      }
    }
  }
#pragma unroll
  for (int i = 0; i < 4; ++i) {
    f32x4 lt = l_[i];
#pragma unroll
    for (int off = 1; off < 16; off <<= 1)
#pragma unroll
      for (int r = 0; r < 4; ++r) lt[r] += __shfl_xor(lt[r], off);
#pragma unroll
    for (int r = 0; r < 4; ++r) {
      float inv = 1.0f / lt[r];
      int row = b * T_ + m0 + i * 16 + q * 4 + r;
      uint16_t* op = o + (size_t)row * D_ + h * HDm;
#pragma unroll
      for (int n = 0; n < 4; ++n)
        op[n * 16 + ln] = (uint16_t)bf16rn(o_[i][n][r] * inv);
    }
  }
}

extern "C" void kernel_launch(void* const* d_in, const int* in_sizes, int n_in,
                              void* d_out, int out_size, void* d_ws, size_t ws_size,
                              hipStream_t stream) {
  const float* x   = (const float*)d_in[0];
  const float* Wq  = (const float*)d_in[1];
  const float* Wk  = (const float*)d_in[2];
  const float* Wv  = (const float*)d_in[3];
  const float* Wp  = (const float*)d_in[4];
  const float* bp  = (const float*)d_in[5];
  const float* W1  = (const float*)d_in[6];
  const float* b1  = (const float*)d_in[7];
  const float* W2  = (const float*)d_in[8];
  const float* b2  = (const float*)d_in[9];
  const float* g1  = (const float*)d_in[10];
  const float* be1 = (const float*)d_in[11];
  const float* g2  = (const float*)d_in[12];
  const float* be2 = (const float*)d_in[13];
  float* out = (float*)d_out;

  char* ws = (char*)d_ws;
  uint16_t* hbuf  = (uint16_t*)ws;
  uint16_t* qkv   = (uint16_t*)(ws + 25165824ull);
  uint16_t* ob    = (uint16_t*)(ws + 100663296ull);
  uint16_t* ff1   = qkv;
  uint16_t* Wqkvt = (uint16_t*)(ws + 125829120ull);
  uint16_t* Wpt   = (uint16_t*)(ws + 126713856ull);
  uint16_t* W1t   = (uint16_t*)(ws + 127008768ull);
  uint16_t* W2t   = (uint16_t*)(ws + 128188416ull);

  // 1. pack weights to bf16, K-contiguous
  pack_qkv_w<<<(1152 * D_ + 255) / 256, 256, 0, stream>>>(Wq, Wk, Wv, Wqkvt);
  pack_wt<<<(384 * 384 + 255) / 256, 256, 0, stream>>>(Wp, Wpt, 384, 384);
  pack_wt<<<(384 * 1536 + 255) / 256, 256, 0, stream>>>(W1, W1t, 384, 1536);
  pack_wt<<<(1536 * 384 + 255) / 256, 256, 0, stream>>>(W2, W2t, 1536, 384);
  // 2. LN1: x -> h (bf16)
  ln_kernel<<<NROW, 128, 0, stream>>>(x, g1, be1, hbuf);
  // 3. QKV projection: [32768,384] @ [384,1152] -> bf16   (grid: x=M-tiles, y=N-tiles)
  gemm_bf16<<<dim3(NROW / 128, 1152 / 128), 256, 0, stream>>>(
      hbuf, Wqkvt, nullptr, nullptr, qkv, NROW, 1152, 384, 0, 0);
  // 4. MFMA flash attention -> ob (bf16)
  attn_mfma<<<B_ * Hn, 256, 0, stream>>>(qkv, ob);
  // 5. x1 = x + ob@Wp + bp  -> d_out (fp32)
  gemm_bf16<<<dim3(NROW / 128, 384 / 128), 256, 0, stream>>>(
      ob, Wpt, bp, x, out, NROW, 384, 384, 0, 1);
  // 6. LN2: x1 -> h (bf16)
  ln_kernel<<<NROW, 128, 0, stream>>>(out, g2, be2, hbuf);
  // 7. FF1 + ReLU: [32768,384] @ [384,1536] -> bf16
  gemm_bf16<<<dim3(NROW / 128, 1536 / 128), 256, 0, stream>>>(
      hbuf, W1t, b1, nullptr, ff1, NROW, 1536, 384, 1, 0);
  // 8. out = x1 + ff1@W2 + b2 -> d_out (fp32)
  gemm_bf16<<<dim3(NROW / 128, 384 / 128), 256, 0, stream>>>(
      ff1, W2t, b2, out, out, NROW, 384, 1536, 0, 1);
}

// Round 6
// 520.196 us; speedup vs baseline: 1.2283x; 1.0391x over previous
//
#include <hip/hip_runtime.h>
#include <cstdint>
#include <cstddef>

#define D_   384
#define Hn   6
#define HDm  64
#define T_   256
#define B_   128
#define NROW (B_ * T_)   // 32768

typedef __bf16  bf16x8 __attribute__((ext_vector_type(8)));
typedef float   f32x4  __attribute__((ext_vector_type(4)));
typedef const __attribute__((address_space(1))) void gvoid;
typedef __attribute__((address_space(3))) void lvoid;

// ---------- helpers ----------
__device__ inline uint32_t bf16rn(float f) {
  uint32_t u = __float_as_uint(f);
  return (u + 0x7FFFu + ((u >> 16) & 1u)) >> 16;
}

// ---------- LayerNorm: fp32 in -> bf16 out, one 128-thread block per row ----------
__global__ __launch_bounds__(128) void ln_kernel(const float* __restrict__ x,
                                                 const float* __restrict__ g,
                                                 const float* __restrict__ b,
                                                 uint16_t* __restrict__ out) {
  int row = blockIdx.x, tid = threadIdx.x;
  const float* xr = x + (size_t)row * D_;
  float v0 = xr[tid], v1 = xr[tid + 128], v2 = xr[tid + 256];
  float s  = v0 + v1 + v2;
  float ss = v0 * v0 + v1 * v1 + v2 * v2;
#pragma unroll
  for (int off = 32; off > 0; off >>= 1) {
    s  += __shfl_down(s, off);
    ss += __shfl_down(ss, off);
  }
  __shared__ float red[4];
  if ((tid & 63) == 0) { red[(tid >> 6) * 2] = s; red[(tid >> 6) * 2 + 1] = ss; }
  __syncthreads();
  float S = red[0] + red[2], SS = red[1] + red[3];
  float mu  = S * (1.0f / D_);
  float var = SS * (1.0f / D_) - mu * mu;
  float inv = rsqrtf(var + 1e-5f);
  uint16_t* orow = out + (size_t)row * D_;
  orow[tid]       = (uint16_t)bf16rn((v0 - mu) * inv * g[tid]       + b[tid]);
  orow[tid + 128] = (uint16_t)bf16rn((v1 - mu) * inv * g[tid + 128] + b[tid + 128]);
  orow[tid + 256] = (uint16_t)bf16rn((v2 - mu) * inv * g[tid + 256] + b[tid + 256]);
}

// ---------- pack Wq/Wk/Wv [H,D,HD] -> bf16 Wt[col=1152][d=384] (K-contiguous) ----------
__global__ __launch_bounds__(256) void pack_qkv_w(const float* __restrict__ Wq,
                                                  const float* __restrict__ Wk,
                                                  const float* __restrict__ Wv,
                                                  uint16_t* __restrict__ Wo) {
  int idx = blockIdx.x * 256 + threadIdx.x;      // 1152*384 total
  if (idx >= 1152 * D_) return;
  int col = idx / D_, d = idx % D_;
  int which = col / 384, c2 = col % 384;
  int h = c2 / HDm, k = c2 % HDm;
  const float* W = (which == 0) ? Wq : (which == 1) ? Wk : Wv;
  Wo[idx] = (uint16_t)bf16rn(W[((size_t)h * D_ + d) * HDm + k]);
}

// ---------- transpose-pack W[K,N] -> bf16 Wt[N,K] ----------
__global__ __launch_bounds__(256) void pack_wt(const float* __restrict__ W,
                                               uint16_t* __restrict__ Wt,
                                               int K, int N) {
  int idx = blockIdx.x * 256 + threadIdx.x;
  if (idx >= K * N) return;
  int n = idx / K, k = idx % K;
  Wt[idx] = (uint16_t)bf16rn(W[(size_t)k * N + n]);
}

// ---------- bf16 MFMA GEMM: C[M,N] = A[M,K] @ Bt[N,K]^T (+bias)(relu)(+resid) ----------
// 128x128 tile, BK=32, 4 waves, 4x4 mfma_f32_16x16x32_bf16 per wave.
// DOUBLE-BUFFERED K-loop: prefetch tile i+1 via global_load_lds right after the
// barrier, compute tile i meanwhile -> load latency gets ~400 cyc of MFMA/ds_read
// head start before the next barrier's vmcnt(0) drain. One barrier per iter.
// Grid: x = M-tiles (256%8==0 so same-A blocks share an XCD), y = N-tiles.
__global__ __launch_bounds__(256) void gemm_bf16(const uint16_t* __restrict__ A,
                                                 const uint16_t* __restrict__ Bt,
                                                 const float* __restrict__ bias,
                                                 const float* __restrict__ resid,
                                                 void* __restrict__ Cout,
                                                 int M, int N, int K,
                                                 int relu, int store_f32) {
  __shared__ uint16_t As[2][128 * 32];   // 2 x 8 KB
  __shared__ uint16_t Bs[2][128 * 32];   // 2 x 8 KB
  int tid = threadIdx.x;
  int bm = blockIdx.x * 128, bn = blockIdx.y * 128;
  int lane = tid & 63, wave = tid >> 6;
  int wm = (wave >> 1) << 6;
  int wn = (wave & 1) << 6;
  int lr = lane & 15;                 // row-within-16
  int q  = lane >> 4;                 // k-chunk selector (0..3)
  int r0 = q << 2;                    // C row base within 16
  int rd_off = (q ^ (lr & 3)) << 3;   // swizzled chunk elem offset within row

  // staging: 2 chunks of 16 B per thread per buffer (512 chunks total)
  int c0 = tid,        row0 = c0 >> 2;
  int c1 = 256 + tid,  row1 = c1 >> 2;
  int g0 = ((c0 & 3) ^ (row0 & 3)) << 3;
  int g1 = ((c1 & 3) ^ (row1 & 3)) << 3;
  const uint16_t* ga0 = A  + (size_t)(bm + row0) * K + g0;
  const uint16_t* ga1 = A  + (size_t)(bm + row1) * K + g1;
  const uint16_t* gb0 = Bt + (size_t)(bn + row0) * K + g0;
  const uint16_t* gb1 = Bt + (size_t)(bn + row1) * K + g1;

  f32x4 acc[4][4];
  const f32x4 zero = {0.f, 0.f, 0.f, 0.f};
#pragma unroll
  for (int i = 0; i < 4; ++i)
#pragma unroll
    for (int j = 0; j < 4; ++j) acc[i][j] = zero;

  int nk = K >> 5;
  // prefetch tile 0 -> buffer 0
  __builtin_amdgcn_global_load_lds((gvoid*)ga0, (lvoid*)((char*)As[0] + c0 * 16), 16, 0, 0);
  __builtin_amdgcn_global_load_lds((gvoid*)gb0, (lvoid*)((char*)Bs[0] + c0 * 16), 16, 0, 0);
  __builtin_amdgcn_global_load_lds((gvoid*)ga1, (lvoid*)((char*)As[0] + c1 * 16), 16, 0, 0);
  __builtin_amdgcn_global_load_lds((gvoid*)gb1, (lvoid*)((char*)Bs[0] + c1 * 16), 16, 0, 0);

  for (int i = 0; i < nk; ++i) {
    int cur = i & 1;
    __syncthreads();     // drains vmcnt -> buf[cur] staged; prior reads of buf[cur^1] done
    if (i + 1 < nk) {
      int nxt = cur ^ 1, ko = (i + 1) << 5;
      __builtin_amdgcn_global_load_lds((gvoid*)(ga0 + ko), (lvoid*)((char*)As[nxt] + c0 * 16), 16, 0, 0);
      __builtin_amdgcn_global_load_lds((gvoid*)(gb0 + ko), (lvoid*)((char*)Bs[nxt] + c0 * 16), 16, 0, 0);
      __builtin_amdgcn_global_load_lds((gvoid*)(ga1 + ko), (lvoid*)((char*)As[nxt] + c1 * 16), 16, 0, 0);
      __builtin_amdgcn_global_load_lds((gvoid*)(gb1 + ko), (lvoid*)((char*)Bs[nxt] + c1 * 16), 16, 0, 0);
    }

    bf16x8 af[4], bfr[4];
#pragma unroll
    for (int ii = 0; ii < 4; ++ii)
      af[ii] = *(const bf16x8*)&As[cur][(wm + ii * 16 + lr) * 32 + rd_off];
#pragma unroll
    for (int j = 0; j < 4; ++j)
      bfr[j] = *(const bf16x8*)&Bs[cur][(wn + j * 16 + lr) * 32 + rd_off];
#pragma unroll
    for (int ii = 0; ii < 4; ++ii)
#pragma unroll
      for (int j = 0; j < 4; ++j)
        acc[ii][j] = __builtin_amdgcn_mfma_f32_16x16x32_bf16(af[ii], bfr[j], acc[ii][j], 0, 0, 0);
  }

#pragma unroll
  for (int i = 0; i < 4; ++i) {
#pragma unroll
    for (int r = 0; r < 4; ++r) {
      int rr = bm + wm + i * 16 + r0 + r;
#pragma unroll
      for (int j = 0; j < 4; ++j) {
        int col = bn + wn + j * 16 + lr;
        float v = acc[i][j][r];
        if (bias)  v += bias[col];
        if (relu)  v = fmaxf(v, 0.0f);
        if (resid) v += resid[(size_t)rr * N + col];
        if (store_f32) ((float*)Cout)[(size_t)rr * N + col] = v;
        else           ((uint16_t*)Cout)[(size_t)rr * N + col] = (uint16_t)bf16rn(v);
      }
    }
  }
}

// ---------- MFMA flash attention: one block per (b,h), 4 waves, wave w = rows w*64..w*64+63 ----------
// qkv (bf16) row (b*T+t): cols [0,384)=q(h*64+d), [384,768)=k, [768,1152)=v
__global__ __launch_bounds__(256, 2) void attn_mfma(const uint16_t* __restrict__ qkv,
                                                    uint16_t* __restrict__ o) {
  __shared__ uint16_t Kt[64 * 72];        // K-tile [s][d], pad 72 (9216 B)
  __shared__ uint16_t Vt[64 * 72];        // V-tile transposed [d][s], pad 72 (9216 B)
  __shared__ uint16_t Pb[4 * 64 * 72];    // per-wave P staging (36864 B)
  int bh = blockIdx.x;
  int b = bh / Hn, h = bh % Hn;
  int tid = threadIdx.x;
  int lane = tid & 63, w = tid >> 6;
  int ln = lane & 15, q = lane >> 4;
  int kq = q * 8;
  int m0 = w * 64;
  const uint16_t* base = qkv + (size_t)b * T_ * 1152;

  bf16x8 af[4][2];
#pragma unroll
  for (int i = 0; i < 4; ++i)
#pragma unroll
    for (int ks = 0; ks < 2; ++ks)
      af[i][ks] = *(const bf16x8*)(base + (size_t)(m0 + i * 16 + ln) * 1152 + h * HDm + ks * 32 + kq);

  f32x4 o_[4][4], m_[4], l_[4];
  const f32x4 zero = {0.f, 0.f, 0.f, 0.f};
#pragma unroll
  for (int i = 0; i < 4; ++i) {
    m_[i] = {-1e30f, -1e30f, -1e30f, -1e30f};
    l_[i] = zero;
#pragma unroll
    for (int n = 0; n < 4; ++n) o_[i][n] = zero;
  }
  const float cs = 0.07362222f;  // (1/sqrt(384)) * log2(e)

  for (int jt = 0; jt < 4; ++jt) {
    if (jt) __syncthreads();
#pragma unroll
    for (int t = 0; t < 2; ++t) {
      int c = t * 256 + tid;
      int s = c >> 3, d0 = (c & 7) << 3;
      *(uint4*)&Kt[s * 72 + d0] =
          *(const uint4*)(base + (size_t)(jt * 64 + s) * 1152 + 384 + h * HDm + d0);
    }
    {
      int sv = tid & 63, dv = (tid >> 6) << 4;
      const uint16_t* gv = base + (size_t)(jt * 64 + sv) * 1152 + 768 + h * HDm + dv;
      uint16_t tmp[16];
      *(uint4*)&tmp[0] = *(const uint4*)gv;
      *(uint4*)&tmp[8] = *(const uint4*)(gv + 8);
#pragma unroll
      for (int jj = 0; jj < 16; ++jj) Vt[(dv + jj) * 72 + sv] = tmp[jj];
    }
    __syncthreads();

    if (w >= jt) {
      f32x4 s2[4][4];
#pragma unroll
      for (int i = 0; i < 4; ++i)
#pragma unroll
        for (int j = 0; j < 4; ++j) s2[i][j] = zero;
#pragma unroll
      for (int ks = 0; ks < 2; ++ks) {
        bf16x8 bf[4];
#pragma unroll
        for (int j = 0; j < 4; ++j)
          bf[j] = *(const bf16x8*)&Kt[(j * 16 + ln) * 72 + ks * 32 + kq];
#pragma unroll
        for (int i = 0; i < 4; ++i)
#pragma unroll
          for (int j = 0; j < 4; ++j)
            s2[i][j] = __builtin_amdgcn_mfma_f32_16x16x32_bf16(af[i][ks], bf[j], s2[i][j], 0, 0, 0);
      }
#pragma unroll
      for (int i = 0; i < 4; ++i) {
#pragma unroll
        for (int j = 0; j < 4; ++j)
#pragma unroll
          for (int r = 0; r < 4; ++r) s2[i][j][r] *= cs;
        if (jt == w) {
#pragma unroll
          for (int j = 0; j < 4; ++j)
#pragma unroll
            for (int r = 0; r < 4; ++r)
              if (j * 16 + ln > i * 16 + q * 4 + r) s2[i][j][r] = -1e30f;
        }
        f32x4 rm;
#pragma unroll
        for (int r = 0; r < 4; ++r)
          rm[r] = fmaxf(fmaxf(s2[i][0][r], s2[i][1][r]), fmaxf(s2[i][2][r], s2[i][3][r]));
#pragma unroll
        for (int off = 1; off < 16; off <<= 1)
#pragma unroll
          for (int r = 0; r < 4; ++r)
            rm[r] = fmaxf(rm[r], __shfl_xor(rm[r], off));
        f32x4 mn, al, ps;
#pragma unroll
        for (int r = 0; r < 4; ++r) {
          mn[r] = fmaxf(m_[i][r], rm[r]);
          al[r] = exp2f(m_[i][r] - mn[r]);
          ps[r] = 0.f;
        }
        m_[i] = mn;
#pragma unroll
        for (int j = 0; j < 4; ++j)
#pragma unroll
          for (int r = 0; r < 4; ++r) {
            float p = exp2f(s2[i][j][r] - mn[r]);
            s2[i][j][r] = p;
            ps[r] += p;
          }
#pragma unroll
        for (int r = 0; r < 4; ++r) l_[i][r] = l_[i][r] * al[r] + ps[r];
#pragma unroll
        for (int n = 0; n < 4; ++n)
#pragma unroll
          for (int r = 0; r < 4; ++r) o_[i][n][r] *= al[r];
#pragma unroll
        for (int j = 0; j < 4; ++j)
#pragma unroll
          for (int r = 0; r < 4; ++r)
            Pb[w * 4608 + (i * 16 + q * 4 + r) * 72 + j * 16 + ln] =
                (uint16_t)bf16rn(s2[i][j][r]);
      }
      bf16x8 pa[4][2];
#pragma unroll
      for (int i = 0; i < 4; ++i)
#pragma unroll
        for (int ks = 0; ks < 2; ++ks)
          pa[i][ks] = *(const bf16x8*)&Pb[w * 4608 + (i * 16 + ln) * 72 + ks * 32 + kq];
#pragma unroll
      for (int n = 0; n < 4; ++n) {
        bf16x8 bv0 = *(const bf16x8*)&Vt[(n * 16 + ln) * 72 + kq];
        bf16x8 bv1 = *(const bf16x8*)&Vt[(n * 16 + ln) * 72 + 32 + kq];
#pragma unroll
        for (int i = 0; i < 4; ++i) {
          o_[i][n] = __builtin_amdgcn_mfma_f32_16x16x32_bf16(pa[i][0], bv0, o_[i][n], 0, 0, 0);
          o_[i][n] = __builtin_amdgcn_mfma_f32_16x16x32_bf16(pa[i][1], bv1, o_[i][n], 0, 0, 0);
        }
      }
    }
  }
#pragma unroll
  for (int i = 0; i < 4; ++i) {
    f32x4 lt = l_[i];
#pragma unroll
    for (int off = 1; off < 16; off <<= 1)
#pragma unroll
      for (int r = 0; r < 4; ++r) lt[r] += __shfl_xor(lt[r], off);
#pragma unroll
    for (int r = 0; r < 4; ++r) {
      float inv = 1.0f / lt[r];
      int row = b * T_ + m0 + i * 16 + q * 4 + r;
      uint16_t* op = o + (size_t)row * D_ + h * HDm;
#pragma unroll
      for (int n = 0; n < 4; ++n)
        op[n * 16 + ln] = (uint16_t)bf16rn(o_[i][n][r] * inv);
    }
  }
}

extern "C" void kernel_launch(void* const* d_in, const int* in_sizes, int n_in,
                              void* d_out, int out_size, void* d_ws, size_t ws_size,
                              hipStream_t stream) {
  const float* x   = (const float*)d_in[0];
  const float* Wq  = (const float*)d_in[1];
  const float* Wk  = (const float*)d_in[2];
  const float* Wv  = (const float*)d_in[3];
  const float* Wp  = (const float*)d_in[4];
  const float* bp  = (const float*)d_in[5];
  const float* W1  = (const float*)d_in[6];
  const float* b1  = (const float*)d_in[7];
  const float* W2  = (const float*)d_in[8];
  const float* b2  = (const float*)d_in[9];
  const float* g1  = (const float*)d_in[10];
  const float* be1 = (const float*)d_in[11];
  const float* g2  = (const float*)d_in[12];
  const float* be2 = (const float*)d_in[13];
  float* out = (float*)d_out;

  char* ws = (char*)d_ws;
  uint16_t* hbuf  = (uint16_t*)ws;
  uint16_t* qkv   = (uint16_t*)(ws + 25165824ull);
  uint16_t* ob    = (uint16_t*)(ws + 100663296ull);
  uint16_t* ff1   = qkv;
  uint16_t* Wqkvt = (uint16_t*)(ws + 125829120ull);
  uint16_t* Wpt   = (uint16_t*)(ws + 126713856ull);
  uint16_t* W1t   = (uint16_t*)(ws + 127008768ull);
  uint16_t* W2t   = (uint16_t*)(ws + 128188416ull);

  // 1. pack weights to bf16, K-contiguous
  pack_qkv_w<<<(1152 * D_ + 255) / 256, 256, 0, stream>>>(Wq, Wk, Wv, Wqkvt);
  pack_wt<<<(384 * 384 + 255) / 256, 256, 0, stream>>>(Wp, Wpt, 384, 384);
  pack_wt<<<(384 * 1536 + 255) / 256, 256, 0, stream>>>(W1, W1t, 384, 1536);
  pack_wt<<<(1536 * 384 + 255) / 256, 256, 0, stream>>>(W2, W2t, 1536, 384);
  // 2. LN1: x -> h (bf16)
  ln_kernel<<<NROW, 128, 0, stream>>>(x, g1, be1, hbuf);
  // 3. QKV projection: [32768,384] @ [384,1152] -> bf16   (grid: x=M-tiles, y=N-tiles)
  gemm_bf16<<<dim3(NROW / 128, 1152 / 128), 256, 0, stream>>>(
      hbuf, Wqkvt, nullptr, nullptr, qkv, NROW, 1152, 384, 0, 0);
  // 4. MFMA flash attention -> ob (bf16)
  attn_mfma<<<B_ * Hn, 256, 0, stream>>>(qkv, ob);
  // 5. x1 = x + ob@Wp + bp  -> d_out (fp32)
  gemm_bf16<<<dim3(NROW / 128, 384 / 128), 256, 0, stream>>>(
      ob, Wpt, bp, x, out, NROW, 384, 384, 0, 1);
  // 6. LN2: x1 -> h (bf16)
  ln_kernel<<<NROW, 128, 0, stream>>>(out, g2, be2, hbuf);
  // 7. FF1 + ReLU: [32768,384] @ [384,1536] -> bf16
  gemm_bf16<<<dim3(NROW / 128, 1536 / 128), 256, 0, stream>>>(
      hbuf, W1t, b1, nullptr, ff1, NROW, 1536, 384, 1, 0);
  // 8. out = x1 + ff1@W2 + b2 -> d_out (fp32)
  gemm_bf16<<<dim3(NROW / 128, 384 / 128), 256, 0, stream>>>(
      ff1, W2t, b2, out, out, NROW, 384, 1536, 0, 1);
}